// Round 4
// baseline (437.263 us; speedup 1.0000x reference)
//
#include <hip/hip_runtime.h>
#include <hip/hip_bf16.h>
#include <cstddef>

typedef __attribute__((ext_vector_type(8))) short bf16x8;   // MFMA A/B operand
typedef __attribute__((ext_vector_type(4))) float f32x4;    // MFMA C/D operand
typedef __attribute__((ext_vector_type(4))) unsigned short us4;
typedef __attribute__((ext_vector_type(8))) unsigned short us8;
typedef unsigned short u16;

// fp32 -> bf16 bits, round-to-nearest-even
__device__ __forceinline__ u16 f2bf(float f) {
    unsigned u = __builtin_bit_cast(unsigned, f);
    u += 0x7FFFu + ((u >> 16) & 1u);
    return (u16)(u >> 16);
}
__device__ __forceinline__ float bf2f(u16 h) {
    unsigned u = ((unsigned)h) << 16;
    return __builtin_bit_cast(float, u);
}

// ---------------------------------------------------------------------------
// split_rm: fp32 array -> bf16 hi/lo planes, same row-major layout.
// n4 = element count / 4.
// ---------------------------------------------------------------------------
__global__ __launch_bounds__(256) void split_rm(const float* __restrict__ in,
                                                u16* __restrict__ hi,
                                                u16* __restrict__ lo, int n4) {
    int i = blockIdx.x * 256 + threadIdx.x;
    const int stride = gridDim.x * 256;
    for (; i < n4; i += stride) {
        f32x4 v = ((const f32x4*)in)[i];
        us4 h, l;
#pragma unroll
        for (int e = 0; e < 4; ++e) {
            u16 hb = f2bf(v[e]);
            h[e] = hb;
            l[e] = f2bf(v[e] - bf2f(hb));
        }
        ((us4*)hi)[i] = h;
        ((us4*)lo)[i] = l;
    }
}

// ---------------------------------------------------------------------------
// split_T: fp32 [R][C] (row stride inRS) -> transposed bf16 hi/lo planes
// [C][R] (row stride outRS), LDS 64x64 tiled, coalesced both sides.
// grid.x = C/64, grid.y = R/64.
// ---------------------------------------------------------------------------
__global__ __launch_bounds__(256) void split_T(const float* __restrict__ in, int inRS,
                                               u16* __restrict__ oh,
                                               u16* __restrict__ ol, int outRS) {
    __shared__ u16 Th[64][68], Tl[64][68];  // 68-pad: 4-way conflict on scalar
                                            // transpose stores (prep-only, ok)
    const int tid = threadIdx.x;
    const int sr = tid >> 4;          // 0..15
    const int sc = (tid & 15) * 4;    // 0..60
    const size_t r0 = (size_t)blockIdx.y * 64;
    const size_t c0 = (size_t)blockIdx.x * 64;

#pragma unroll
    for (int i = 0; i < 4; ++i) {
        int r = sr + i * 16;
        f32x4 v = *(const f32x4*)(in + (r0 + r) * inRS + c0 + sc);
#pragma unroll
        for (int e = 0; e < 4; ++e) {
            u16 hb = f2bf(v[e]);
            Th[sc + e][r] = hb;
            Tl[sc + e][r] = f2bf(v[e] - bf2f(hb));
        }
    }
    __syncthreads();
#pragma unroll
    for (int i = 0; i < 4; ++i) {
        int r = sr + i * 16;  // out-row within tile (c-dim)
        *(us4*)&oh[(c0 + r) * outRS + r0 + sc] = *(const us4*)&Th[r][sc];
        *(us4*)&ol[(c0 + r) * outRS + r0 + sc] = *(const us4*)&Tl[r][sc];
    }
}

// ---------------------------------------------------------------------------
// gemm_bf: C[M,N] = (Ah+Al)[M,K] @ (Bh+Bl)^T[N,K], pre-split bf16 planes in,
// keeping hi*hi + hi*lo + lo*hi (split-bf16, ~2^-17 rel err).
// 128x128 tile, BK=32, 256 thr (4 waves 2x2), 4x4 16x16x32 frags/wave.
// LDS [128][40] u16: 80B row stride -> ~2-way aliasing on b128 reads (free).
// mode 0: fp32 C.  mode 1 (qkv): cols 0..1023 -> scaled(1/8) split Q planes,
// 1024..2047 -> split K planes, 2048.. -> fp32 vtmp.  grid%8==0.
// ---------------------------------------------------------------------------
__global__ __launch_bounds__(256) void gemm_bf(
    const u16* __restrict__ Ah_g, const u16* __restrict__ Al_g,
    const u16* __restrict__ Bh_g, const u16* __restrict__ Bl_g,
    int N, int K, int gy, int mode,
    float* __restrict__ Cf,
    u16* __restrict__ qsh, u16* __restrict__ qsl,
    u16* __restrict__ ksh, u16* __restrict__ ksl,
    float* __restrict__ vtmp) {
    __shared__ u16 Ah[128][40], Al[128][40];
    __shared__ u16 Bh[128][40], Bl[128][40];  // [n][k]

    const int tid = threadIdx.x;

    // XCD-aware swizzle (grid%8==0); bm fastest -> B-panel L2 reuse
    const int nwg = gridDim.x;
    const int swz = (blockIdx.x & 7) * (nwg >> 3) + (blockIdx.x >> 3);
    const int bm = (swz % gy) * 128;
    const int bn = (swz / gy) * 128;

    // staging: thread owns 4 chunks (rows r0+32c), us4 along k at akc
    const int arow0 = tid >> 3;       // 0..31
    const int akc   = (tid & 7) * 4;  // 0,4,..,28

    const u16* pAh = Ah_g + (size_t)(bm + arow0) * K + akc;
    const u16* pAl = Al_g + (size_t)(bm + arow0) * K + akc;
    const u16* pBh = Bh_g + (size_t)(bn + arow0) * K + akc;
    const u16* pBl = Bl_g + (size_t)(bn + arow0) * K + akc;

    us4 rah[4], ral[4], rbh[4], rbl[4];
#pragma unroll
    for (int c = 0; c < 4; ++c) {
        const size_t o = (size_t)(32 * c) * K;
        rah[c] = *(const us4*)(pAh + o);
        ral[c] = *(const us4*)(pAl + o);
        rbh[c] = *(const us4*)(pBh + o);
        rbl[c] = *(const us4*)(pBl + o);
    }

    const int lane = tid & 63;
    const int w    = tid >> 6;
    const int wm   = (w >> 1) * 64;
    const int wn   = (w & 1) * 64;
    const int lr   = lane & 15;
    const int lg   = lane >> 4;
    const int kb   = lg * 8;

    f32x4 acc[4][4] = {};

    const int NK = K >> 5;
    for (int kt = 0; kt < NK; ++kt) {
#pragma unroll
        for (int c = 0; c < 4; ++c) {
            const int row = arow0 + c * 32;
            *(us4*)&Ah[row][akc] = rah[c];
            *(us4*)&Al[row][akc] = ral[c];
            *(us4*)&Bh[row][akc] = rbh[c];
            *(us4*)&Bl[row][akc] = rbl[c];
        }
        __syncthreads();

        if (kt + 1 < NK) {
            pAh += 32; pAl += 32; pBh += 32; pBl += 32;
#pragma unroll
            for (int c = 0; c < 4; ++c) {
                const size_t o = (size_t)(32 * c) * K;
                rah[c] = *(const us4*)(pAh + o);
                ral[c] = *(const us4*)(pAl + o);
                rbh[c] = *(const us4*)(pBh + o);
                rbl[c] = *(const us4*)(pBl + o);
            }
        }

        bf16x8 fah[4], fal[4], fbh[4], fbl[4];
#pragma unroll
        for (int m = 0; m < 4; ++m) {
            fah[m] = __builtin_bit_cast(bf16x8, *(const us8*)&Ah[wm + m * 16 + lr][kb]);
            fal[m] = __builtin_bit_cast(bf16x8, *(const us8*)&Al[wm + m * 16 + lr][kb]);
        }
#pragma unroll
        for (int n = 0; n < 4; ++n) {
            fbh[n] = __builtin_bit_cast(bf16x8, *(const us8*)&Bh[wn + n * 16 + lr][kb]);
            fbl[n] = __builtin_bit_cast(bf16x8, *(const us8*)&Bl[wn + n * 16 + lr][kb]);
        }
#pragma unroll
        for (int m = 0; m < 4; ++m)
#pragma unroll
            for (int n = 0; n < 4; ++n) {
                acc[m][n] = __builtin_amdgcn_mfma_f32_16x16x32_bf16(fah[m], fbh[n], acc[m][n], 0, 0, 0);
                acc[m][n] = __builtin_amdgcn_mfma_f32_16x16x32_bf16(fah[m], fbl[n], acc[m][n], 0, 0, 0);
                acc[m][n] = __builtin_amdgcn_mfma_f32_16x16x32_bf16(fal[m], fbh[n], acc[m][n], 0, 0, 0);
            }
        __syncthreads();
    }

    // epilogue: C/D layout col=lane&15, row=lg*4+reg
    const int orow = bm + wm + lg * 4;
    if (mode == 0) {
        const int ocol = bn + wn + lr;
#pragma unroll
        for (int m = 0; m < 4; ++m)
#pragma unroll
            for (int r = 0; r < 4; ++r) {
                const size_t row = (size_t)(orow + m * 16 + r);
#pragma unroll
                for (int n = 0; n < 4; ++n)
                    Cf[row * N + ocol + n * 16] = acc[m][n][r];
            }
    } else {
        const int sec = bn >> 10;                   // uniform per block
        const int cbase = (bn & 1023) + wn + lr;    // col within 1024 section
#pragma unroll
        for (int m = 0; m < 4; ++m)
#pragma unroll
            for (int r = 0; r < 4; ++r) {
                const size_t row = (size_t)(orow + m * 16 + r);
#pragma unroll
                for (int n = 0; n < 4; ++n) {
                    float v = acc[m][n][r];
                    const size_t idx = row * 1024 + cbase + n * 16;
                    if (sec == 0) {          // Q, fold 1/sqrt(dh)=0.125
                        v *= 0.125f;
                        u16 hb = f2bf(v);
                        qsh[idx] = hb;
                        qsl[idx] = f2bf(v - bf2f(hb));
                    } else if (sec == 1) {   // K
                        u16 hb = f2bf(v);
                        ksh[idx] = hb;
                        ksl[idx] = f2bf(v - bf2f(hb));
                    } else {                 // V (fp32, transposed+split later)
                        vtmp[idx] = v;
                    }
                }
            }
    }
}

// ---------------------------------------------------------------------------
// attn_bf: flash causal attention on pre-split planes.
// qs/ks planes: [4096][1024] (token-major, head at h*64; Q pre-scaled).
// vt planes: [1024][4096] = [h*64+d][token] (transposed).
// o planes (split): [4096][1024].
// Grid 1024: bh = bid>>5 (same-bh q-blocks adjacent -> KV L2 reuse),
// qb = 31-(bid&31) heavy-first. 4 waves; wave w owns q-rows [w*16, w*16+16).
// QK^T and PV split-bf16 (3 MFMAs/frag pair); softmax fp32.
// LDS [64][72] u16: 144B stride -> 2-way aliasing on b128 (free).
// P wave-private -> no barrier between P-store and PV read (in-order DS pipe).
// ---------------------------------------------------------------------------
__global__ __launch_bounds__(256) void attn_bf(
    const u16* __restrict__ qsh, const u16* __restrict__ qsl,
    const u16* __restrict__ ksh, const u16* __restrict__ ksl,
    const u16* __restrict__ vth, const u16* __restrict__ vtl,
    u16* __restrict__ oh, u16* __restrict__ ol) {
    __shared__ u16 Qh[64][72], Ql[64][72];
    __shared__ u16 Kh[64][72], Kl[64][72];
    __shared__ u16 Vh[64][72], Vl[64][72];  // [d][k]
    __shared__ u16 Ph[64][72], Pl[64][72];  // [q][k]

    const int tid  = threadIdx.x;
    const int lane = tid & 63;
    const int w    = tid >> 6;
    const int wq0  = w * 16;
    const int lr   = lane & 15;
    const int lg   = lane >> 4;
    const int kb   = lg * 8;

    const int bh = blockIdx.x >> 5;
    const int qb = 31 - (blockIdx.x & 31);  // heavy-first
    const int b  = bh >> 4;
    const int h  = bh & 15;

    const int sr = tid >> 4;          // 0..15
    const int sc = (tid & 15) * 4;    // 0..60

    // ---- stage Q (pre-scaled, pre-split) ----
#pragma unroll
    for (int i = 0; i < 4; ++i) {
        int r = sr + i * 16;
        const size_t g = (size_t)(b * 2048 + qb * 64 + r) * 1024 + h * 64 + sc;
        *(us4*)&Qh[r][sc] = *(const us4*)(qsh + g);
        *(us4*)&Ql[r][sc] = *(const us4*)(qsl + g);
    }

    float m_i[4], l_i[4];
    f32x4 acc_o[4] = {};
#pragma unroll
    for (int r = 0; r < 4; ++r) { m_i[r] = -1e30f; l_i[r] = 0.f; }

    for (int kt = 0; kt <= qb; ++kt) {
        // ---- stage K [k][d] and V^T [d][k], all vector us4 ----
#pragma unroll
        for (int i = 0; i < 4; ++i) {
            int r = sr + i * 16;
            const size_t gk = (size_t)(b * 2048 + kt * 64 + r) * 1024 + h * 64 + sc;
            *(us4*)&Kh[r][sc] = *(const us4*)(ksh + gk);
            *(us4*)&Kl[r][sc] = *(const us4*)(ksl + gk);
            const size_t gv = (size_t)(h * 64 + r) * 4096 + b * 2048 + kt * 64 + sc;
            *(us4*)&Vh[r][sc] = *(const us4*)(vth + gv);
            *(us4*)&Vl[r][sc] = *(const us4*)(vtl + gv);
        }
        __syncthreads();

        // ---- S = Q K^T : 2 k-steps x 4 col-frags x 3 MFMAs ----
        f32x4 accs[4] = {};
#pragma unroll
        for (int ks = 0; ks < 2; ++ks) {
            bf16x8 aqh = __builtin_bit_cast(bf16x8, *(const us8*)&Qh[wq0 + lr][ks * 32 + kb]);
            bf16x8 aql = __builtin_bit_cast(bf16x8, *(const us8*)&Ql[wq0 + lr][ks * 32 + kb]);
#pragma unroll
            for (int n = 0; n < 4; ++n) {
                bf16x8 bkh = __builtin_bit_cast(bf16x8, *(const us8*)&Kh[n * 16 + lr][ks * 32 + kb]);
                bf16x8 bkl = __builtin_bit_cast(bf16x8, *(const us8*)&Kl[n * 16 + lr][ks * 32 + kb]);
                accs[n] = __builtin_amdgcn_mfma_f32_16x16x32_bf16(aqh, bkh, accs[n], 0, 0, 0);
                accs[n] = __builtin_amdgcn_mfma_f32_16x16x32_bf16(aqh, bkl, accs[n], 0, 0, 0);
                accs[n] = __builtin_amdgcn_mfma_f32_16x16x32_bf16(aql, bkh, accs[n], 0, 0, 0);
            }
        }

        // ---- causal mask (diagonal tile) ----
        if (kt == qb) {
#pragma unroll
            for (int n = 0; n < 4; ++n)
#pragma unroll
                for (int r = 0; r < 4; ++r)
                    if (n * 16 + lr > wq0 + lg * 4 + r) accs[n][r] = -1e30f;
        }

        // ---- online softmax (rows in 16-lane groups) ----
#pragma unroll
        for (int r = 0; r < 4; ++r) {
            float pm = fmaxf(fmaxf(accs[0][r], accs[1][r]),
                             fmaxf(accs[2][r], accs[3][r]));
#pragma unroll
            for (int off = 1; off < 16; off <<= 1)
                pm = fmaxf(pm, __shfl_xor(pm, off));
            float mnew  = fmaxf(m_i[r], pm);
            float alpha = __expf(m_i[r] - mnew);
            float ps = 0.f;
            const int prow = wq0 + lg * 4 + r;
#pragma unroll
            for (int n = 0; n < 4; ++n) {
                float p = __expf(accs[n][r] - mnew);
                u16 ph = f2bf(p);
                Ph[prow][n * 16 + lr] = ph;
                Pl[prow][n * 16 + lr] = f2bf(p - bf2f(ph));
                ps += p;
            }
#pragma unroll
            for (int off = 1; off < 16; off <<= 1)
                ps += __shfl_xor(ps, off);
            l_i[r] = l_i[r] * alpha + ps;
            m_i[r] = mnew;
#pragma unroll
            for (int n = 0; n < 4; ++n) acc_o[n][r] *= alpha;
        }
        // P wave-private: DS pipe is in-order within a wave, no barrier needed

        // ---- O += P V ----
#pragma unroll
        for (int ks = 0; ks < 2; ++ks) {
            bf16x8 aph = __builtin_bit_cast(bf16x8, *(const us8*)&Ph[wq0 + lr][ks * 32 + kb]);
            bf16x8 apl = __builtin_bit_cast(bf16x8, *(const us8*)&Pl[wq0 + lr][ks * 32 + kb]);
#pragma unroll
            for (int n = 0; n < 4; ++n) {
                bf16x8 bvh = __builtin_bit_cast(bf16x8, *(const us8*)&Vh[n * 16 + lr][ks * 32 + kb]);
                bf16x8 bvl = __builtin_bit_cast(bf16x8, *(const us8*)&Vl[n * 16 + lr][ks * 32 + kb]);
                acc_o[n] = __builtin_amdgcn_mfma_f32_16x16x32_bf16(aph, bvh, acc_o[n], 0, 0, 0);
                acc_o[n] = __builtin_amdgcn_mfma_f32_16x16x32_bf16(aph, bvl, acc_o[n], 0, 0, 0);
                acc_o[n] = __builtin_amdgcn_mfma_f32_16x16x32_bf16(apl, bvh, acc_o[n], 0, 0, 0);
            }
        }
        __syncthreads();  // PV done before next tile overwrites K/V
    }

    // ---- epilogue: split O for the proj GEMM ----
#pragma unroll
    for (int r = 0; r < 4; ++r) {
        float inv = 1.0f / l_i[r];
        const size_t q = (size_t)(qb * 64 + wq0 + lg * 4 + r);
#pragma unroll
        for (int n = 0; n < 4; ++n) {
            float v = acc_o[n][r] * inv;
            const size_t idx = ((size_t)b * 2048 + q) * 1024 + h * 64 + n * 16 + lr;
            u16 hb = f2bf(v);
            oh[idx] = hb;
            ol[idx] = f2bf(v - bf2f(hb));
        }
    }
}

// ---------------------------------------------------------------------------
// Workspace layout (needs 80 MB; stream-ordered aliases noted):
//   0MB  wqkvT_h[3072][1024]   6MB
//   6MB  wqkvT_l               6MB
//  12MB  wprojT_h[1024][1024]  2MB
//  14MB  wprojT_l              2MB
//  16MB  xh[4096][1024]        8MB   } consumed by gemm1, then reused as
//  24MB  xl                    8MB   } vth/vtl [1024][4096] (prep_v writes)
//  32MB  qsh[4096][1024]       8MB
//  40MB  qsl                   8MB
//  48MB  ksh                   8MB
//  56MB  ksl                   8MB
//  64MB  vtmp f32[4096][1024] 16MB   } consumed by prep_v, then reused as
//                                    } oh/ol [4096][1024] (attn writes)
// ---------------------------------------------------------------------------
extern "C" void kernel_launch(void* const* d_in, const int* in_sizes, int n_in,
                              void* d_out, int out_size, void* d_ws, size_t ws_size,
                              hipStream_t stream) {
    const float* x      = (const float*)d_in[0];  // [2,2048,1024]
    const float* w_qkv  = (const float*)d_in[1];  // [1024,3072]
    const float* w_proj = (const float*)d_in[2];  // [1024,1024]
    float* out = (float*)d_out;                   // [2,2048,1024]

    char* ws = (char*)d_ws;
    const size_t MB = 1u << 20;
    u16* wqkvT_h  = (u16*)(ws + 0 * MB);
    u16* wqkvT_l  = (u16*)(ws + 6 * MB);
    u16* wprojT_h = (u16*)(ws + 12 * MB);
    u16* wprojT_l = (u16*)(ws + 14 * MB);
    u16* xh       = (u16*)(ws + 16 * MB);
    u16* xl       = (u16*)(ws + 24 * MB);
    u16* qsh      = (u16*)(ws + 32 * MB);
    u16* qsl      = (u16*)(ws + 40 * MB);
    u16* ksh      = (u16*)(ws + 48 * MB);
    u16* ksl      = (u16*)(ws + 56 * MB);
    float* vtmp   = (float*)(ws + 64 * MB);
    u16* vth = xh;                    // alias: x planes dead after gemm1
    u16* vtl = xl;
    u16* oh = (u16*)vtmp;             // alias: vtmp dead after prep_v
    u16* ol = oh + (size_t)4096 * 1024;

    // prep: split x; transpose+split weights
    split_rm<<<2048, 256, 0, stream>>>(x, xh, xl, 4096 * 1024 / 4);
    split_T<<<dim3(48, 16), 256, 0, stream>>>(w_qkv, 3072, wqkvT_h, wqkvT_l, 1024);
    split_T<<<dim3(16, 16), 256, 0, stream>>>(w_proj, 1024, wprojT_h, wprojT_l, 1024);

    // 1) qkv GEMM (M=4096,N=3072,K=1024), epilogue emits split Q(scaled)/K + fp32 V
    gemm_bf<<<dim3(768), 256, 0, stream>>>(xh, xl, wqkvT_h, wqkvT_l,
                                           3072, 1024, 32, 1,
                                           nullptr, qsh, qsl, ksh, ksl, vtmp);

    // prep_v: vtmp [4096][1024] -> transposed split planes [1024][4096]
    split_T<<<dim3(16, 64), 256, 0, stream>>>(vtmp, 1024, vth, vtl, 4096);

    // 2) flash causal attention -> split O planes
    attn_bf<<<dim3(1024), 256, 0, stream>>>(qsh, qsl, ksh, ksl, vth, vtl, oh, ol);

    // 3) out = O @ w_proj (M=4096,N=1024,K=1024), fp32 out
    gemm_bf<<<dim3(256), 256, 0, stream>>>(oh, ol, wprojT_h, wprojT_l,
                                           1024, 1024, 32, 0,
                                           out, nullptr, nullptr, nullptr, nullptr, nullptr);
}

// Round 5
// 328.350 us; speedup vs baseline: 1.3317x; 1.3317x over previous
//
#include <hip/hip_runtime.h>
#include <hip/hip_bf16.h>
#include <cstddef>

typedef __attribute__((ext_vector_type(8))) short bf16x8;   // MFMA A/B operand
typedef __attribute__((ext_vector_type(4))) float f32x4;    // MFMA C/D operand
typedef __attribute__((ext_vector_type(4))) unsigned short us4;
typedef __attribute__((ext_vector_type(8))) unsigned short us8;
typedef unsigned short u16;
typedef unsigned int u32;

// fp32 -> bf16 bits, round-to-nearest-even
__device__ __forceinline__ u16 f2bf(float f) {
    unsigned u = __builtin_bit_cast(unsigned, f);
    u += 0x7FFFu + ((u >> 16) & 1u);
    return (u16)(u >> 16);
}
__device__ __forceinline__ float bf2f(u16 h) {
    unsigned u = ((unsigned)h) << 16;
    return __builtin_bit_cast(float, u);
}

// async global->LDS, 16B per lane (wave-uniform LDS base + lane*16)
__device__ __forceinline__ void gl_lds16(const u16* g, u16* l) {
    __builtin_amdgcn_global_load_lds(
        (const __attribute__((address_space(1))) u32*)g,
        (__attribute__((address_space(3))) u32*)l, 16, 0, 0);
}

// swizzled b128 read from linear [64][64]-u16 LDS tile: logical chunk ck (16B)
// of row lives at physical chunk ck ^ (row&7)
__device__ __forceinline__ bf16x8 ldswz(const u16* base, int row, int ck) {
    const u16* p = base + row * 64 + ((ck ^ (row & 7)) << 3);
    return __builtin_bit_cast(bf16x8, *(const us8*)p);
}

// ---------------------------------------------------------------------------
// split_rm: fp32 array -> bf16 hi/lo planes, same row-major layout.
// ---------------------------------------------------------------------------
__global__ __launch_bounds__(256) void split_rm(const float* __restrict__ in,
                                                u16* __restrict__ hi,
                                                u16* __restrict__ lo, int n4) {
    int i = blockIdx.x * 256 + threadIdx.x;
    const int stride = gridDim.x * 256;
    for (; i < n4; i += stride) {
        f32x4 v = ((const f32x4*)in)[i];
        us4 h, l;
#pragma unroll
        for (int e = 0; e < 4; ++e) {
            u16 hb = f2bf(v[e]);
            h[e] = hb;
            l[e] = f2bf(v[e] - bf2f(hb));
        }
        ((us4*)hi)[i] = h;
        ((us4*)lo)[i] = l;
    }
}

// ---------------------------------------------------------------------------
// split_T: fp32 [R][C] (row stride inRS) -> transposed bf16 hi/lo planes
// [C][R] (row stride outRS), LDS 64x64 tiled.
// ---------------------------------------------------------------------------
__global__ __launch_bounds__(256) void split_T(const float* __restrict__ in, int inRS,
                                               u16* __restrict__ oh,
                                               u16* __restrict__ ol, int outRS) {
    __shared__ u16 Th[64][68], Tl[64][68];
    const int tid = threadIdx.x;
    const int sr = tid >> 4;
    const int sc = (tid & 15) * 4;
    const size_t r0 = (size_t)blockIdx.y * 64;
    const size_t c0 = (size_t)blockIdx.x * 64;

#pragma unroll
    for (int i = 0; i < 4; ++i) {
        int r = sr + i * 16;
        f32x4 v = *(const f32x4*)(in + (r0 + r) * inRS + c0 + sc);
#pragma unroll
        for (int e = 0; e < 4; ++e) {
            u16 hb = f2bf(v[e]);
            Th[sc + e][r] = hb;
            Tl[sc + e][r] = f2bf(v[e] - bf2f(hb));
        }
    }
    __syncthreads();
#pragma unroll
    for (int i = 0; i < 4; ++i) {
        int r = sr + i * 16;
        *(us4*)&oh[(c0 + r) * outRS + r0 + sc] = *(const us4*)&Th[r][sc];
        *(us4*)&ol[(c0 + r) * outRS + r0 + sc] = *(const us4*)&Tl[r][sc];
    }
}

// ---------------------------------------------------------------------------
// gemm_bf: C[M,N] = (Ah+Al)[M,K] @ (Bh+Bl)^T[N,K], pre-split bf16 planes,
// keeping hi*hi + hi*lo + lo*hi. 128x128 tile, BK=32, 256 thr (4 waves 2x2).
// mode 1 (qkv): epilogue emits scaled split Q, split K, fp32 V.
// ---------------------------------------------------------------------------
__global__ __launch_bounds__(256) void gemm_bf(
    const u16* __restrict__ Ah_g, const u16* __restrict__ Al_g,
    const u16* __restrict__ Bh_g, const u16* __restrict__ Bl_g,
    int N, int K, int gy, int mode,
    float* __restrict__ Cf,
    u16* __restrict__ qsh, u16* __restrict__ qsl,
    u16* __restrict__ ksh, u16* __restrict__ ksl,
    float* __restrict__ vtmp) {
    __shared__ u16 Ah[128][40], Al[128][40];
    __shared__ u16 Bh[128][40], Bl[128][40];  // [n][k]

    const int tid = threadIdx.x;
    const int nwg = gridDim.x;
    const int swz = (blockIdx.x & 7) * (nwg >> 3) + (blockIdx.x >> 3);
    const int bm = (swz % gy) * 128;
    const int bn = (swz / gy) * 128;

    const int arow0 = tid >> 3;
    const int akc   = (tid & 7) * 4;

    const u16* pAh = Ah_g + (size_t)(bm + arow0) * K + akc;
    const u16* pAl = Al_g + (size_t)(bm + arow0) * K + akc;
    const u16* pBh = Bh_g + (size_t)(bn + arow0) * K + akc;
    const u16* pBl = Bl_g + (size_t)(bn + arow0) * K + akc;

    us4 rah[4], ral[4], rbh[4], rbl[4];
#pragma unroll
    for (int c = 0; c < 4; ++c) {
        const size_t o = (size_t)(32 * c) * K;
        rah[c] = *(const us4*)(pAh + o);
        ral[c] = *(const us4*)(pAl + o);
        rbh[c] = *(const us4*)(pBh + o);
        rbl[c] = *(const us4*)(pBl + o);
    }

    const int lane = tid & 63;
    const int w    = tid >> 6;
    const int wm   = (w >> 1) * 64;
    const int wn   = (w & 1) * 64;
    const int lr   = lane & 15;
    const int lg   = lane >> 4;
    const int kb   = lg * 8;

    f32x4 acc[4][4] = {};

    const int NK = K >> 5;
    for (int kt = 0; kt < NK; ++kt) {
#pragma unroll
        for (int c = 0; c < 4; ++c) {
            const int row = arow0 + c * 32;
            *(us4*)&Ah[row][akc] = rah[c];
            *(us4*)&Al[row][akc] = ral[c];
            *(us4*)&Bh[row][akc] = rbh[c];
            *(us4*)&Bl[row][akc] = rbl[c];
        }
        __syncthreads();

        if (kt + 1 < NK) {
            pAh += 32; pAl += 32; pBh += 32; pBl += 32;
#pragma unroll
            for (int c = 0; c < 4; ++c) {
                const size_t o = (size_t)(32 * c) * K;
                rah[c] = *(const us4*)(pAh + o);
                ral[c] = *(const us4*)(pAl + o);
                rbh[c] = *(const us4*)(pBh + o);
                rbl[c] = *(const us4*)(pBl + o);
            }
        }

        bf16x8 fah[4], fal[4], fbh[4], fbl[4];
#pragma unroll
        for (int m = 0; m < 4; ++m) {
            fah[m] = __builtin_bit_cast(bf16x8, *(const us8*)&Ah[wm + m * 16 + lr][kb]);
            fal[m] = __builtin_bit_cast(bf16x8, *(const us8*)&Al[wm + m * 16 + lr][kb]);
        }
#pragma unroll
        for (int n = 0; n < 4; ++n) {
            fbh[n] = __builtin_bit_cast(bf16x8, *(const us8*)&Bh[wn + n * 16 + lr][kb]);
            fbl[n] = __builtin_bit_cast(bf16x8, *(const us8*)&Bl[wn + n * 16 + lr][kb]);
        }
#pragma unroll
        for (int m = 0; m < 4; ++m)
#pragma unroll
            for (int n = 0; n < 4; ++n) {
                acc[m][n] = __builtin_amdgcn_mfma_f32_16x16x32_bf16(fah[m], fbh[n], acc[m][n], 0, 0, 0);
                acc[m][n] = __builtin_amdgcn_mfma_f32_16x16x32_bf16(fah[m], fbl[n], acc[m][n], 0, 0, 0);
                acc[m][n] = __builtin_amdgcn_mfma_f32_16x16x32_bf16(fal[m], fbh[n], acc[m][n], 0, 0, 0);
            }
        __syncthreads();
    }

    const int orow = bm + wm + lg * 4;
    if (mode == 0) {
        const int ocol = bn + wn + lr;
#pragma unroll
        for (int m = 0; m < 4; ++m)
#pragma unroll
            for (int r = 0; r < 4; ++r) {
                const size_t row = (size_t)(orow + m * 16 + r);
#pragma unroll
                for (int n = 0; n < 4; ++n)
                    Cf[row * N + ocol + n * 16] = acc[m][n][r];
            }
    } else {
        const int sec = bn >> 10;
        const int cbase = (bn & 1023) + wn + lr;
#pragma unroll
        for (int m = 0; m < 4; ++m)
#pragma unroll
            for (int r = 0; r < 4; ++r) {
                const size_t row = (size_t)(orow + m * 16 + r);
#pragma unroll
                for (int n = 0; n < 4; ++n) {
                    float v = acc[m][n][r];
                    const size_t idx = row * 1024 + cbase + n * 16;
                    if (sec == 0) {
                        v *= 0.125f;
                        u16 hb = f2bf(v);
                        qsh[idx] = hb;
                        qsl[idx] = f2bf(v - bf2f(hb));
                    } else if (sec == 1) {
                        u16 hb = f2bf(v);
                        ksh[idx] = hb;
                        ksl[idx] = f2bf(v - bf2f(hb));
                    } else {
                        vtmp[idx] = v;
                    }
                }
            }
    }
}

// ---------------------------------------------------------------------------
// attn_v2: flash causal attention, pipelined global_load_lds staging.
// 512 thr = 8 waves; QBLK=128 (wave w owns q-rows [w*16,w*16+16)); KVBLK=64.
// Grid 512: first 256 blocks = heavy q-tiles (qt 15..8), second 256 = light
// (qt 0..7) -> each CU hosts ~one heavy + one light block (2 blocks/CU).
// Q in registers. K/V in linear [64][64]-u16 LDS, chunk-XOR swizzle
// (phys = log ^ (row&7)) applied via inverse-swizzled global sources
// (global_load_lds writes linearly). P in padded LDS [128][72].
// Pipeline per tile: wait vmcnt(2) [own K landed] / barrier / QK^T+softmax /
// wait vmcnt(0)+lgkm / barrier / issue K(t+1) / PV / lgkm / barrier /
// issue V(t+1).  Raw s_barrier (NOT __syncthreads -> would drain vmcnt).
// ---------------------------------------------------------------------------
__global__ __launch_bounds__(512, 4) void attn_v2(
    const u16* __restrict__ qsh, const u16* __restrict__ qsl,
    const u16* __restrict__ ksh, const u16* __restrict__ ksl,
    const u16* __restrict__ vth, const u16* __restrict__ vtl,
    u16* __restrict__ oh, u16* __restrict__ ol) {
    __shared__ u16 KH[4096], KL[4096], VH[4096], VL[4096];  // [64][64] linear
    __shared__ u16 Ph[128][72], Pl[128][72];                 // padded

    const int tid  = threadIdx.x;
    const int lane = tid & 63;
    const int w    = tid >> 6;       // 0..7
    const int wq0  = w * 16;
    const int lr   = lane & 15;
    const int lg   = lane >> 4;

    // block -> (b,h,qt): pair heavy (qt 15..8) with light (qt 0..7)
    const int bid  = blockIdx.x;
    const int half = bid >> 8;
    const int idx  = bid & 255;
    const int bh   = idx & 31;
    const int jj   = idx >> 5;                  // 0..7
    const int qt   = half ? jj : (15 - jj);
    const int b    = bh >> 4;
    const int h    = bh & 15;
    const int NT   = 2 * qt + 2;
    const size_t tokb = (size_t)b * 2048;

    // ---- Q fragments in registers (A-operand: row=wq0+lr, k=ks*32+lg*8+j) ----
    const size_t qtok = tokb + (size_t)qt * 128 + wq0 + lr;
    const u16* qph = qsh + qtok * 1024 + h * 64 + lg * 8;
    const u16* qpl = qsl + qtok * 1024 + h * 64 + lg * 8;
    bf16x8 aqh[2], aql[2];
    aqh[0] = __builtin_bit_cast(bf16x8, *(const us8*)qph);
    aqh[1] = __builtin_bit_cast(bf16x8, *(const us8*)(qph + 32));
    aql[0] = __builtin_bit_cast(bf16x8, *(const us8*)qpl);
    aql[1] = __builtin_bit_cast(bf16x8, *(const us8*)(qpl + 32));

    // ---- staging geometry: wave w stages rows [w*8, w*8+8) of each array ----
    const int rl    = lane >> 3;                 // 0..7 (row within call)
    const int rbase = w * 8;
    const int cl    = (lane & 7) ^ rl;           // inverse-swizzled source chunk
    const u16* kh0 = ksh + (tokb + rbase + rl) * 1024 + h * 64 + cl * 8;
    const u16* kl0 = ksl + (tokb + rbase + rl) * 1024 + h * 64 + cl * 8;
    const u16* vh0 = vth + (size_t)(h * 64 + rbase + rl) * 4096 + tokb + cl * 8;
    const u16* vl0 = vtl + (size_t)(h * 64 + rbase + rl) * 4096 + tokb + cl * 8;
    u16* ldsKH = KH + rbase * 64;
    u16* ldsKL = KL + rbase * 64;
    u16* ldsVH = VH + rbase * 64;
    u16* ldsVL = VL + rbase * 64;

    // prologue: issue K(0) then V(0)  (2 K-calls, 2 V-calls per wave)
    gl_lds16(kh0, ldsKH);
    gl_lds16(kl0, ldsKL);
    gl_lds16(vh0, ldsVH);
    gl_lds16(vl0, ldsVL);

    float m_i[4], l_i[4];
    f32x4 acc_o[4] = {};
#pragma unroll
    for (int r = 0; r < 4; ++r) { m_i[r] = -1e30f; l_i[r] = 0.f; }

    for (int kt = 0; kt < NT; ++kt) {
        const int koff = kt * 64 - qt * 128;
        const bool active = !(kt == NT - 1 && wq0 < 64);  // wave fully masked?

        asm volatile("s_waitcnt vmcnt(2)" ::: "memory");  // own K(t) landed
        __builtin_amdgcn_s_barrier();                     // all K(t) visible

        f32x4 accs[4] = {};
        if (active) {
            // ---- S = Q K^T ----
#pragma unroll
            for (int ks = 0; ks < 2; ++ks) {
                bf16x8 a0 = aqh[ks], a1 = aql[ks];
#pragma unroll
                for (int n = 0; n < 4; ++n) {
                    bf16x8 bkh = ldswz(KH, n * 16 + lr, ks * 4 + lg);
                    bf16x8 bkl = ldswz(KL, n * 16 + lr, ks * 4 + lg);
                    accs[n] = __builtin_amdgcn_mfma_f32_16x16x32_bf16(a0, bkh, accs[n], 0, 0, 0);
                    accs[n] = __builtin_amdgcn_mfma_f32_16x16x32_bf16(a0, bkl, accs[n], 0, 0, 0);
                    accs[n] = __builtin_amdgcn_mfma_f32_16x16x32_bf16(a1, bkh, accs[n], 0, 0, 0);
                }
            }
            // ---- causal mask (tail tiles only) ----
            if (koff + 63 > wq0) {
#pragma unroll
                for (int n = 0; n < 4; ++n)
#pragma unroll
                    for (int rr = 0; rr < 4; ++rr)
                        if (koff + n * 16 + lr > wq0 + 4 * lg + rr)
                            accs[n][rr] = -1e30f;
            }
            // ---- online softmax (rows in 16-lane groups) ----
#pragma unroll
            for (int rr = 0; rr < 4; ++rr) {
                float pm = fmaxf(fmaxf(accs[0][rr], accs[1][rr]),
                                 fmaxf(accs[2][rr], accs[3][rr]));
#pragma unroll
                for (int off = 1; off < 16; off <<= 1)
                    pm = fmaxf(pm, __shfl_xor(pm, off));
                float mnew  = fmaxf(m_i[rr], pm);
                float alpha = __expf(m_i[rr] - mnew);
                float ps = 0.f;
                const int prow = wq0 + 4 * lg + rr;
#pragma unroll
                for (int n = 0; n < 4; ++n) {
                    float p = __expf(accs[n][rr] - mnew);
                    u16 phb = f2bf(p);
                    Ph[prow][n * 16 + lr] = phb;
                    Pl[prow][n * 16 + lr] = f2bf(p - bf2f(phb));
                    ps += p;
                }
#pragma unroll
                for (int off = 1; off < 16; off <<= 1)
                    ps += __shfl_xor(ps, off);
                l_i[rr] = l_i[rr] * alpha + ps;
                m_i[rr] = mnew;
#pragma unroll
                for (int n = 0; n < 4; ++n) acc_o[n][rr] *= alpha;
            }
        }

        asm volatile("s_waitcnt vmcnt(0)" ::: "memory");   // own V(t) landed
        asm volatile("s_waitcnt lgkmcnt(0)" ::: "memory"); // K reads + P writes done
        __builtin_amdgcn_s_barrier();                      // V visible; K free

        if (kt + 1 < NT) {  // issue K(t+1) -- overlaps PV
            gl_lds16(kh0 + (size_t)(kt + 1) * 65536, ldsKH);
            gl_lds16(kl0 + (size_t)(kt + 1) * 65536, ldsKL);
        }

        if (active) {
            // ---- O += P V ----
#pragma unroll
            for (int ks = 0; ks < 2; ++ks) {
                bf16x8 aph = __builtin_bit_cast(bf16x8, *(const us8*)&Ph[wq0 + lr][ks * 32 + lg * 8]);
                bf16x8 apl = __builtin_bit_cast(bf16x8, *(const us8*)&Pl[wq0 + lr][ks * 32 + lg * 8]);
#pragma unroll
                for (int n = 0; n < 4; ++n) {
                    bf16x8 bvh = ldswz(VH, n * 16 + lr, ks * 4 + lg);
                    bf16x8 bvl = ldswz(VL, n * 16 + lr, ks * 4 + lg);
                    acc_o[n] = __builtin_amdgcn_mfma_f32_16x16x32_bf16(aph, bvh, acc_o[n], 0, 0, 0);
                    acc_o[n] = __builtin_amdgcn_mfma_f32_16x16x32_bf16(aph, bvl, acc_o[n], 0, 0, 0);
                    acc_o[n] = __builtin_amdgcn_mfma_f32_16x16x32_bf16(apl, bvh, acc_o[n], 0, 0, 0);
                }
            }
        }

        asm volatile("s_waitcnt lgkmcnt(0)" ::: "memory"); // V reads done
        __builtin_amdgcn_s_barrier();

        if (kt + 1 < NT) {  // issue V(t+1) -- overlaps next QK^T
            gl_lds16(vh0 + (kt + 1) * 64, ldsVH);
            gl_lds16(vl0 + (kt + 1) * 64, ldsVL);
        }
    }

    // ---- epilogue: split O planes for the proj GEMM ----
#pragma unroll
    for (int rr = 0; rr < 4; ++rr) {
        float inv = 1.0f / l_i[rr];
        const size_t q = (size_t)qt * 128 + wq0 + 4 * lg + rr;
#pragma unroll
        for (int n = 0; n < 4; ++n) {
            float v = acc_o[n][rr] * inv;
            const size_t oidx = (tokb + q) * 1024 + h * 64 + n * 16 + lr;
            u16 hb = f2bf(v);
            oh[oidx] = hb;
            ol[oidx] = f2bf(v - bf2f(hb));
        }
    }
}

// ---------------------------------------------------------------------------
// Workspace (80 MB), stream-ordered aliases:
//   0 wqkvT_h 6MB | 6 wqkvT_l | 12 wprojT_h 2MB | 14 wprojT_l
//   16 xh 8MB / 24 xl 8MB   (dead after gemm1 -> reused as vth/vtl)
//   32 qsh / 40 qsl / 48 ksh / 56 ksl (8MB each)
//   64 vtmp 16MB            (dead after prep_v -> reused as oh/ol)
// ---------------------------------------------------------------------------
extern "C" void kernel_launch(void* const* d_in, const int* in_sizes, int n_in,
                              void* d_out, int out_size, void* d_ws, size_t ws_size,
                              hipStream_t stream) {
    const float* x      = (const float*)d_in[0];
    const float* w_qkv  = (const float*)d_in[1];
    const float* w_proj = (const float*)d_in[2];
    float* out = (float*)d_out;

    char* ws = (char*)d_ws;
    const size_t MB = 1u << 20;
    u16* wqkvT_h  = (u16*)(ws + 0 * MB);
    u16* wqkvT_l  = (u16*)(ws + 6 * MB);
    u16* wprojT_h = (u16*)(ws + 12 * MB);
    u16* wprojT_l = (u16*)(ws + 14 * MB);
    u16* xh       = (u16*)(ws + 16 * MB);
    u16* xl       = (u16*)(ws + 24 * MB);
    u16* qsh      = (u16*)(ws + 32 * MB);
    u16* qsl      = (u16*)(ws + 40 * MB);
    u16* ksh      = (u16*)(ws + 48 * MB);
    u16* ksl      = (u16*)(ws + 56 * MB);
    float* vtmp   = (float*)(ws + 64 * MB);
    u16* vth = xh;
    u16* vtl = xl;
    u16* oh = (u16*)vtmp;
    u16* ol = oh + (size_t)4096 * 1024;

    split_rm<<<2048, 256, 0, stream>>>(x, xh, xl, 4096 * 1024 / 4);
    split_T<<<dim3(48, 16), 256, 0, stream>>>(w_qkv, 3072, wqkvT_h, wqkvT_l, 1024);
    split_T<<<dim3(16, 16), 256, 0, stream>>>(w_proj, 1024, wprojT_h, wprojT_l, 1024);

    // 1) qkv GEMM: epilogue emits split Q(scaled)/K + fp32 V
    gemm_bf<<<dim3(768), 256, 0, stream>>>(xh, xl, wqkvT_h, wqkvT_l,
                                           3072, 1024, 32, 1,
                                           nullptr, qsh, qsl, ksh, ksl, vtmp);

    // prep_v: vtmp [4096][1024] -> transposed split planes [1024][4096]
    split_T<<<dim3(16, 64), 256, 0, stream>>>(vtmp, 1024, vth, vtl, 4096);

    // 2) pipelined flash causal attention
    attn_v2<<<dim3(512), 512, 0, stream>>>(qsh, qsl, ksh, ksl, vth, vtl, oh, ol);

    // 3) out = O @ w_proj
    gemm_bf<<<dim3(256), 256, 0, stream>>>(oh, ol, wprojT_h, wprojT_l,
                                           1024, 1024, 32, 0,
                                           out, nullptr, nullptr, nullptr, nullptr, nullptr);
}

// Round 6
// 322.594 us; speedup vs baseline: 1.3555x; 1.0178x over previous
//
#include <hip/hip_runtime.h>
#include <hip/hip_bf16.h>
#include <cstddef>

typedef __attribute__((ext_vector_type(8))) short bf16x8;   // MFMA A/B operand
typedef __attribute__((ext_vector_type(4))) float f32x4;    // MFMA C/D operand
typedef __attribute__((ext_vector_type(4))) unsigned short us4;
typedef __attribute__((ext_vector_type(8))) unsigned short us8;
typedef unsigned short u16;
typedef unsigned int u32;

// fp32 -> bf16 bits, round-to-nearest-even
__device__ __forceinline__ u16 f2bf(float f) {
    unsigned u = __builtin_bit_cast(unsigned, f);
    u += 0x7FFFu + ((u >> 16) & 1u);
    return (u16)(u >> 16);
}
__device__ __forceinline__ float bf2f(u16 h) {
    unsigned u = ((unsigned)h) << 16;
    return __builtin_bit_cast(float, u);
}

// async global->LDS, 16B per lane (wave-uniform LDS base + lane*16)
__device__ __forceinline__ void gl_lds16(const u16* g, u16* l) {
    __builtin_amdgcn_global_load_lds(
        (const __attribute__((address_space(1))) u32*)g,
        (__attribute__((address_space(3))) u32*)l, 16, 0, 0);
}

template <int N>
__device__ __forceinline__ void wait_vmcnt() {
    if constexpr (N == 8)      asm volatile("s_waitcnt vmcnt(8)" ::: "memory");
    else if constexpr (N == 6) asm volatile("s_waitcnt vmcnt(6)" ::: "memory");
    else                       asm volatile("s_waitcnt vmcnt(0)" ::: "memory");
}

// ---------------------------------------------------------------------------
// split_rm: fp32 array -> bf16 hi/lo planes, same row-major layout.
// ---------------------------------------------------------------------------
__global__ __launch_bounds__(256) void split_rm(const float* __restrict__ in,
                                                u16* __restrict__ hi,
                                                u16* __restrict__ lo, int n4) {
    int i = blockIdx.x * 256 + threadIdx.x;
    const int stride = gridDim.x * 256;
    for (; i < n4; i += stride) {
        f32x4 v = ((const f32x4*)in)[i];
        us4 h, l;
#pragma unroll
        for (int e = 0; e < 4; ++e) {
            u16 hb = f2bf(v[e]);
            h[e] = hb;
            l[e] = f2bf(v[e] - bf2f(hb));
        }
        ((us4*)hi)[i] = h;
        ((us4*)lo)[i] = l;
    }
}

// ---------------------------------------------------------------------------
// split_T: fp32 [R][C] (row stride inRS) -> transposed bf16 hi/lo planes
// [C][R] (row stride outRS), LDS 64x64 tiled.
// ---------------------------------------------------------------------------
__global__ __launch_bounds__(256) void split_T(const float* __restrict__ in, int inRS,
                                               u16* __restrict__ oh,
                                               u16* __restrict__ ol, int outRS) {
    __shared__ u16 Th[64][68], Tl[64][68];
    const int tid = threadIdx.x;
    const int sr = tid >> 4;
    const int sc = (tid & 15) * 4;
    const size_t r0 = (size_t)blockIdx.y * 64;
    const size_t c0 = (size_t)blockIdx.x * 64;

#pragma unroll
    for (int i = 0; i < 4; ++i) {
        int r = sr + i * 16;
        f32x4 v = *(const f32x4*)(in + (r0 + r) * inRS + c0 + sc);
#pragma unroll
        for (int e = 0; e < 4; ++e) {
            u16 hb = f2bf(v[e]);
            Th[sc + e][r] = hb;
            Tl[sc + e][r] = f2bf(v[e] - bf2f(hb));
        }
    }
    __syncthreads();
#pragma unroll
    for (int i = 0; i < 4; ++i) {
        int r = sr + i * 16;
        *(us4*)&oh[(c0 + r) * outRS + r0 + sc] = *(const us4*)&Th[r][sc];
        *(us4*)&ol[(c0 + r) * outRS + r0 + sc] = *(const us4*)&Tl[r][sc];
    }
}

// ---------------------------------------------------------------------------
// gemm_bf2<BN>: C[M,N] = (Ah+Al)[M,K] @ (Bh+Bl)^T[N,K], pre-split bf16
// planes, keeping hi*hi + hi*lo + lo*hi.  128xBN tile, BK=32, 256 thr
// (4 waves 2x2; per-wave 64 x BN/2).  Staging via global_load_lds (16B),
// double-buffered LDS, counted vmcnt, raw s_barrier (attn_v2 pattern).
// LDS planes [rows][32] u16 linear; chunk-XOR swizzle phys=lg^((row>>1)&3)
// applied via inverse-swizzled global sources -> conflict-free b128 reads.
// mode 1 (qkv): epilogue emits scaled split Q, split K, fp32 V.
// Requires M%128==0, N%BN==0, K%32==0, grid%8==0.
// ---------------------------------------------------------------------------
template <int BN>
__global__ __launch_bounds__(256, 2) void gemm_bf2(
    const u16* __restrict__ Ah_g, const u16* __restrict__ Al_g,
    const u16* __restrict__ Bh_g, const u16* __restrict__ Bl_g,
    int N, int K, int gy, int mode,
    float* __restrict__ Cf,
    u16* __restrict__ qsh, u16* __restrict__ qsl,
    u16* __restrict__ ksh, u16* __restrict__ ksl,
    float* __restrict__ vtmp) {
    constexpr int NB    = BN / 32;            // N-frags per wave
    constexpr int ASZ   = 128 * 32;           // u16 per A plane
    constexpr int BSZ   = BN * 32;
    constexpr int SET   = 2 * ASZ + 2 * BSZ;  // one buffer set (4 planes)
    constexpr int BCALL = BN / 64;            // B calls per plane per wave
    constexpr int NCALL = 4 + 2 * BCALL;      // per-wave calls per set
    __shared__ u16 LB[2 * SET];

    const int tid  = threadIdx.x;
    const int lane = tid & 63;
    const int w    = tid >> 6;

    // XCD-aware swizzle (grid%8==0); bm fastest -> B-panel L2 reuse
    const int nwg = gridDim.x;
    const int swz = (blockIdx.x & 7) * (nwg >> 3) + (blockIdx.x >> 3);
    const int bm = (swz % gy) * 128;
    const int bn = (swz / gy) * BN;

    // staging source geometry: call covers 16 rows; lane -> (row, phys chunk)
    const int srow = lane >> 2;                      // 0..15
    const int c_l  = (lane & 3) ^ ((lane >> 3) & 3); // logical chunk at phys lane&3

    const u16* pA[2][2];
    const u16* pB[2][BCALL];
#pragma unroll
    for (int j = 0; j < 2; ++j) {
        const size_t r = (size_t)(bm + w * 32 + j * 16 + srow);
        pA[0][j] = Ah_g + r * K + c_l * 8;
        pA[1][j] = Al_g + r * K + c_l * 8;
    }
#pragma unroll
    for (int j = 0; j < BCALL; ++j) {
        const size_t r = (size_t)(bn + w * (BN / 4) + j * 16 + srow);
        pB[0][j] = Bh_g + r * K + c_l * 8;
        pB[1][j] = Bl_g + r * K + c_l * 8;
    }

    auto stage = [&](int buf, int kt) {
        u16* s = LB + buf * SET;
        const size_t ko = (size_t)kt * 32;
#pragma unroll
        for (int p = 0; p < 2; ++p)
#pragma unroll
            for (int j = 0; j < 2; ++j)
                gl_lds16(pA[p][j] + ko, s + p * ASZ + (w * 32 + j * 16) * 32);
#pragma unroll
        for (int p = 0; p < 2; ++p)
#pragma unroll
            for (int j = 0; j < BCALL; ++j)
                gl_lds16(pB[p][j] + ko,
                         s + 2 * ASZ + p * BSZ + (w * (BN / 4) + j * 16) * 32);
    };

    const int lr = lane & 15;
    const int lg = lane >> 4;
    const int wm = (w >> 1) * 64;
    const int wn = (w & 1) * (BN / 2);
    const int fc = (lg ^ ((lr >> 1) & 3)) * 8;  // phys chunk offset (u16)

    f32x4 acc[4][NB] = {};

    const int NK = K >> 5;
    // prologue: prefetch sets 0 and 1
    stage(0, 0);
    if (NK > 1) stage(1, 1);

    for (int kt = 0; kt < NK; ++kt) {
        const int cur = kt & 1;
        if (kt + 1 < NK) wait_vmcnt<NCALL>();   // own set(kt) landed
        else             wait_vmcnt<0>();
        __builtin_amdgcn_s_barrier();           // all waves' set(kt) landed

        const u16* s = LB + cur * SET;
        bf16x8 fah[4], fal[4], fbh[NB], fbl[NB];
#pragma unroll
        for (int m = 0; m < 4; ++m) {
            const int ro = (wm + m * 16 + lr) * 32 + fc;
            fah[m] = __builtin_bit_cast(bf16x8, *(const us8*)(s + ro));
            fal[m] = __builtin_bit_cast(bf16x8, *(const us8*)(s + ASZ + ro));
        }
#pragma unroll
        for (int n = 0; n < NB; ++n) {
            const int ro = (wn + n * 16 + lr) * 32 + fc;
            fbh[n] = __builtin_bit_cast(bf16x8, *(const us8*)(s + 2 * ASZ + ro));
            fbl[n] = __builtin_bit_cast(bf16x8, *(const us8*)(s + 2 * ASZ + BSZ + ro));
        }
#pragma unroll
        for (int m = 0; m < 4; ++m)
#pragma unroll
            for (int n = 0; n < NB; ++n) {
                acc[m][n] = __builtin_amdgcn_mfma_f32_16x16x32_bf16(fah[m], fbh[n], acc[m][n], 0, 0, 0);
                acc[m][n] = __builtin_amdgcn_mfma_f32_16x16x32_bf16(fah[m], fbl[n], acc[m][n], 0, 0, 0);
                acc[m][n] = __builtin_amdgcn_mfma_f32_16x16x32_bf16(fal[m], fbh[n], acc[m][n], 0, 0, 0);
            }

        asm volatile("s_waitcnt lgkmcnt(0)" ::: "memory");  // own reads done
        __builtin_amdgcn_s_barrier();                       // all reads done
        if (kt + 2 < NK) stage(cur, kt + 2);                // refill freed buf
    }

    // epilogue: C/D layout col=lane&15, row=lg*4+reg
    const int orow = bm + wm + lg * 4;
    if (mode == 0) {
        const int ocol = bn + wn + lr;
#pragma unroll
        for (int m = 0; m < 4; ++m)
#pragma unroll
            for (int r = 0; r < 4; ++r) {
                const size_t row = (size_t)(orow + m * 16 + r);
#pragma unroll
                for (int n = 0; n < NB; ++n)
                    Cf[row * N + ocol + n * 16] = acc[m][n][r];
            }
    } else {
        const int sec = bn >> 10;
        const int cbase = (bn & 1023) + wn + lr;
#pragma unroll
        for (int m = 0; m < 4; ++m)
#pragma unroll
            for (int r = 0; r < 4; ++r) {
                const size_t row = (size_t)(orow + m * 16 + r);
#pragma unroll
                for (int n = 0; n < NB; ++n) {
                    float v = acc[m][n][r];
                    const size_t idx = row * 1024 + cbase + n * 16;
                    if (sec == 0) {          // Q, fold 1/sqrt(dh)
                        v *= 0.125f;
                        u16 hb = f2bf(v);
                        qsh[idx] = hb;
                        qsl[idx] = f2bf(v - bf2f(hb));
                    } else if (sec == 1) {   // K
                        u16 hb = f2bf(v);
                        ksh[idx] = hb;
                        ksl[idx] = f2bf(v - bf2f(hb));
                    } else {                 // V (fp32; transposed+split later)
                        vtmp[idx] = v;
                    }
                }
            }
    }
}

// ---------------------------------------------------------------------------
// attn_v2: flash causal attention, pipelined global_load_lds staging.
// (unchanged from round 5: 118.5 µs, ~925 TF effective)
// ---------------------------------------------------------------------------
__global__ __launch_bounds__(512, 4) void attn_v2(
    const u16* __restrict__ qsh, const u16* __restrict__ qsl,
    const u16* __restrict__ ksh, const u16* __restrict__ ksl,
    const u16* __restrict__ vth, const u16* __restrict__ vtl,
    u16* __restrict__ oh, u16* __restrict__ ol) {
    __shared__ u16 KH[4096], KL[4096], VH[4096], VL[4096];  // [64][64] linear
    __shared__ u16 Ph[128][72], Pl[128][72];                 // padded

    const int tid  = threadIdx.x;
    const int lane = tid & 63;
    const int w    = tid >> 6;
    const int wq0  = w * 16;
    const int lr   = lane & 15;
    const int lg   = lane >> 4;

    const int bid  = blockIdx.x;
    const int half = bid >> 8;
    const int idx  = bid & 255;
    const int bh   = idx & 31;
    const int jj   = idx >> 5;
    const int qt   = half ? jj : (15 - jj);
    const int b    = bh >> 4;
    const int h    = bh & 15;
    const int NT   = 2 * qt + 2;
    const size_t tokb = (size_t)b * 2048;

    const size_t qtok = tokb + (size_t)qt * 128 + wq0 + lr;
    const u16* qph = qsh + qtok * 1024 + h * 64 + lg * 8;
    const u16* qpl = qsl + qtok * 1024 + h * 64 + lg * 8;
    bf16x8 aqh[2], aql[2];
    aqh[0] = __builtin_bit_cast(bf16x8, *(const us8*)qph);
    aqh[1] = __builtin_bit_cast(bf16x8, *(const us8*)(qph + 32));
    aql[0] = __builtin_bit_cast(bf16x8, *(const us8*)qpl);
    aql[1] = __builtin_bit_cast(bf16x8, *(const us8*)(qpl + 32));

    const int rl    = lane >> 3;
    const int rbase = w * 8;
    const int cl    = (lane & 7) ^ rl;
    const u16* kh0 = ksh + (tokb + rbase + rl) * 1024 + h * 64 + cl * 8;
    const u16* kl0 = ksl + (tokb + rbase + rl) * 1024 + h * 64 + cl * 8;
    const u16* vh0 = vth + (size_t)(h * 64 + rbase + rl) * 4096 + tokb + cl * 8;
    const u16* vl0 = vtl + (size_t)(h * 64 + rbase + rl) * 4096 + tokb + cl * 8;
    u16* ldsKH = KH + rbase * 64;
    u16* ldsKL = KL + rbase * 64;
    u16* ldsVH = VH + rbase * 64;
    u16* ldsVL = VL + rbase * 64;

    gl_lds16(kh0, ldsKH);
    gl_lds16(kl0, ldsKL);
    gl_lds16(vh0, ldsVH);
    gl_lds16(vl0, ldsVL);

    float m_i[4], l_i[4];
    f32x4 acc_o[4] = {};
#pragma unroll
    for (int r = 0; r < 4; ++r) { m_i[r] = -1e30f; l_i[r] = 0.f; }

    for (int kt = 0; kt < NT; ++kt) {
        const int koff = kt * 64 - qt * 128;
        const bool active = !(kt == NT - 1 && wq0 < 64);

        asm volatile("s_waitcnt vmcnt(2)" ::: "memory");
        __builtin_amdgcn_s_barrier();

        f32x4 accs[4] = {};
        if (active) {
#pragma unroll
            for (int ks = 0; ks < 2; ++ks) {
                bf16x8 a0 = aqh[ks], a1 = aql[ks];
#pragma unroll
                for (int n = 0; n < 4; ++n) {
                    const int row = n * 16 + lr;
                    const u16* pk = KH + row * 64 + (((ks * 4 + lg) ^ (row & 7)) << 3);
                    bf16x8 bkh = __builtin_bit_cast(bf16x8, *(const us8*)pk);
                    bf16x8 bkl = __builtin_bit_cast(bf16x8, *(const us8*)(pk + 4096));
                    accs[n] = __builtin_amdgcn_mfma_f32_16x16x32_bf16(a0, bkh, accs[n], 0, 0, 0);
                    accs[n] = __builtin_amdgcn_mfma_f32_16x16x32_bf16(a0, bkl, accs[n], 0, 0, 0);
                    accs[n] = __builtin_amdgcn_mfma_f32_16x16x32_bf16(a1, bkh, accs[n], 0, 0, 0);
                }
            }
            if (koff + 63 > wq0) {
#pragma unroll
                for (int n = 0; n < 4; ++n)
#pragma unroll
                    for (int rr = 0; rr < 4; ++rr)
                        if (koff + n * 16 + lr > wq0 + 4 * lg + rr)
                            accs[n][rr] = -1e30f;
            }
#pragma unroll
            for (int rr = 0; rr < 4; ++rr) {
                float pm = fmaxf(fmaxf(accs[0][rr], accs[1][rr]),
                                 fmaxf(accs[2][rr], accs[3][rr]));
#pragma unroll
                for (int off = 1; off < 16; off <<= 1)
                    pm = fmaxf(pm, __shfl_xor(pm, off));
                float mnew  = fmaxf(m_i[rr], pm);
                float alpha = __expf(m_i[rr] - mnew);
                float ps = 0.f;
                const int prow = wq0 + 4 * lg + rr;
#pragma unroll
                for (int n = 0; n < 4; ++n) {
                    float p = __expf(accs[n][rr] - mnew);
                    u16 phb = f2bf(p);
                    Ph[prow][n * 16 + lr] = phb;
                    Pl[prow][n * 16 + lr] = f2bf(p - bf2f(phb));
                    ps += p;
                }
#pragma unroll
                for (int off = 1; off < 16; off <<= 1)
                    ps += __shfl_xor(ps, off);
                l_i[rr] = l_i[rr] * alpha + ps;
                m_i[rr] = mnew;
#pragma unroll
                for (int n = 0; n < 4; ++n) acc_o[n][rr] *= alpha;
            }
        }

        asm volatile("s_waitcnt vmcnt(0)" ::: "memory");
        asm volatile("s_waitcnt lgkmcnt(0)" ::: "memory");
        __builtin_amdgcn_s_barrier();

        if (kt + 1 < NT) {
            gl_lds16(kh0 + (size_t)(kt + 1) * 65536, ldsKH);
            gl_lds16(kl0 + (size_t)(kt + 1) * 65536, ldsKL);
        }

        if (active) {
#pragma unroll
            for (int ks = 0; ks < 2; ++ks) {
                bf16x8 aph = __builtin_bit_cast(bf16x8, *(const us8*)&Ph[wq0 + lr][ks * 32 + lg * 8]);
                bf16x8 apl = __builtin_bit_cast(bf16x8, *(const us8*)&Pl[wq0 + lr][ks * 32 + lg * 8]);
#pragma unroll
                for (int n = 0; n < 4; ++n) {
                    const int row = n * 16 + lr;
                    const u16* pv = VH + row * 64 + (((ks * 4 + lg) ^ (row & 7)) << 3);
                    bf16x8 bvh = __builtin_bit_cast(bf16x8, *(const us8*)pv);
                    bf16x8 bvl = __builtin_bit_cast(bf16x8, *(const us8*)(pv + 4096));
                    acc_o[n] = __builtin_amdgcn_mfma_f32_16x16x32_bf16(aph, bvh, acc_o[n], 0, 0, 0);
                    acc_o[n] = __builtin_amdgcn_mfma_f32_16x16x32_bf16(aph, bvl, acc_o[n], 0, 0, 0);
                    acc_o[n] = __builtin_amdgcn_mfma_f32_16x16x32_bf16(apl, bvh, acc_o[n], 0, 0, 0);
                }
            }
        }

        asm volatile("s_waitcnt lgkmcnt(0)" ::: "memory");
        __builtin_amdgcn_s_barrier();

        if (kt + 1 < NT) {
            gl_lds16(vh0 + (kt + 1) * 64, ldsVH);
            gl_lds16(vl0 + (kt + 1) * 64, ldsVL);
        }
    }

#pragma unroll
    for (int rr = 0; rr < 4; ++rr) {
        float inv = 1.0f / l_i[rr];
        const size_t q = (size_t)qt * 128 + wq0 + 4 * lg + rr;
#pragma unroll
        for (int n = 0; n < 4; ++n) {
            float v = acc_o[n][rr] * inv;
            const size_t oidx = (tokb + q) * 1024 + h * 64 + n * 16 + lr;
            u16 hb = f2bf(v);
            oh[oidx] = hb;
            ol[oidx] = f2bf(v - bf2f(hb));
        }
    }
}

// ---------------------------------------------------------------------------
// Workspace (80 MB), stream-ordered aliases:
//   0 wqkvT_h 6MB | 6 wqkvT_l | 12 wprojT_h 2MB | 14 wprojT_l
//   16 xh 8MB / 24 xl 8MB   (dead after gemm1 -> reused as vth/vtl)
//   32 qsh / 40 qsl / 48 ksh / 56 ksl (8MB each)
//   64 vtmp 16MB            (dead after prep_v -> reused as oh/ol)
// ---------------------------------------------------------------------------
extern "C" void kernel_launch(void* const* d_in, const int* in_sizes, int n_in,
                              void* d_out, int out_size, void* d_ws, size_t ws_size,
                              hipStream_t stream) {
    const float* x      = (const float*)d_in[0];
    const float* w_qkv  = (const float*)d_in[1];
    const float* w_proj = (const float*)d_in[2];
    float* out = (float*)d_out;

    char* ws = (char*)d_ws;
    const size_t MB = 1u << 20;
    u16* wqkvT_h  = (u16*)(ws + 0 * MB);
    u16* wqkvT_l  = (u16*)(ws + 6 * MB);
    u16* wprojT_h = (u16*)(ws + 12 * MB);
    u16* wprojT_l = (u16*)(ws + 14 * MB);
    u16* xh       = (u16*)(ws + 16 * MB);
    u16* xl       = (u16*)(ws + 24 * MB);
    u16* qsh      = (u16*)(ws + 32 * MB);
    u16* qsl      = (u16*)(ws + 40 * MB);
    u16* ksh      = (u16*)(ws + 48 * MB);
    u16* ksl      = (u16*)(ws + 56 * MB);
    float* vtmp   = (float*)(ws + 64 * MB);
    u16* vth = xh;
    u16* vtl = xl;
    u16* oh = (u16*)vtmp;
    u16* ol = oh + (size_t)4096 * 1024;

    split_rm<<<2048, 256, 0, stream>>>(x, xh, xl, 4096 * 1024 / 4);
    split_T<<<dim3(48, 16), 256, 0, stream>>>(w_qkv, 3072, wqkvT_h, wqkvT_l, 1024);
    split_T<<<dim3(16, 16), 256, 0, stream>>>(w_proj, 1024, wprojT_h, wprojT_l, 1024);

    // 1) qkv GEMM (M=4096,N=3072,K=1024): grid 24*32=768 (%8==0)
    gemm_bf2<128><<<dim3(768), 256, 0, stream>>>(xh, xl, wqkvT_h, wqkvT_l,
                                                 3072, 1024, 32, 1,
                                                 nullptr, qsh, qsl, ksh, ksl, vtmp);

    // prep_v: vtmp [4096][1024] -> transposed split planes [1024][4096]
    split_T<<<dim3(16, 64), 256, 0, stream>>>(vtmp, 1024, vth, vtl, 4096);

    // 2) pipelined flash causal attention
    attn_v2<<<dim3(512), 512, 0, stream>>>(qsh, qsl, ksh, ksl, vth, vtl, oh, ol);

    // 3) out = O @ w_proj (M=4096,N=1024,K=1024): BN=64 -> grid 16*32=512
    gemm_bf2<64><<<dim3(512), 256, 0, stream>>>(oh, ol, wprojT_h, wprojT_l,
                                                1024, 1024, 32, 0,
                                                out, nullptr, nullptr, nullptr, nullptr, nullptr);
}

// Round 12
// 296.929 us; speedup vs baseline: 1.4726x; 1.0864x over previous
//
#include <hip/hip_runtime.h>
#include <hip/hip_bf16.h>
#include <cstddef>

typedef __attribute__((ext_vector_type(8))) short bf16x8;   // MFMA A/B operand
typedef __attribute__((ext_vector_type(4))) float f32x4;    // MFMA C/D operand
typedef __attribute__((ext_vector_type(4))) unsigned short us4;
typedef __attribute__((ext_vector_type(8))) unsigned short us8;
typedef unsigned short u16;
typedef unsigned int u32;

// fp32 -> bf16 bits, round-to-nearest-even
__device__ __forceinline__ u16 f2bf(float f) {
    unsigned u = __builtin_bit_cast(unsigned, f);
    u += 0x7FFFu + ((u >> 16) & 1u);
    return (u16)(u >> 16);
}
__device__ __forceinline__ float bf2f(u16 h) {
    unsigned u = ((unsigned)h) << 16;
    return __builtin_bit_cast(float, u);
}

// async global->LDS, 16B per lane (wave-uniform LDS base + lane*16)
__device__ __forceinline__ void gl_lds16(const u16* g, u16* l) {
    __builtin_amdgcn_global_load_lds(
        (const __attribute__((address_space(1))) u32*)g,
        (__attribute__((address_space(3))) u32*)l, 16, 0, 0);
}

template <int N>
__device__ __forceinline__ void wait_vmcnt() {
    if constexpr (N == 10)     asm volatile("s_waitcnt vmcnt(10)" ::: "memory");
    else if constexpr (N == 8) asm volatile("s_waitcnt vmcnt(8)" ::: "memory");
    else if constexpr (N == 6) asm volatile("s_waitcnt vmcnt(6)" ::: "memory");
    else                       asm volatile("s_waitcnt vmcnt(0)" ::: "memory");
}

// ---------------------------------------------------------------------------
// 64x64 transpose+split helper: in[r0..r0+64)[c0..c0+64) -> out[c][r] planes
// ---------------------------------------------------------------------------
__device__ __forceinline__ void tsplit64(const float* __restrict__ in, int inRS,
                                         u16* __restrict__ oh, u16* __restrict__ ol,
                                         int outRS, size_t r0, size_t c0, int tid,
                                         u16 (*Th)[68], u16 (*Tl)[68]) {
    const int sr = tid >> 4;
    const int sc = (tid & 15) * 4;
#pragma unroll
    for (int i = 0; i < 4; ++i) {
        int r = sr + i * 16;
        f32x4 v = *(const f32x4*)(in + (r0 + r) * inRS + c0 + sc);
#pragma unroll
        for (int e = 0; e < 4; ++e) {
            u16 hb = f2bf(v[e]);
            Th[sc + e][r] = hb;
            Tl[sc + e][r] = f2bf(v[e] - bf2f(hb));
        }
    }
    __syncthreads();
#pragma unroll
    for (int i = 0; i < 4; ++i) {
        int r = sr + i * 16;
        *(us4*)&oh[(c0 + r) * outRS + r0 + sc] = *(const us4*)&Th[r][sc];
        *(us4*)&ol[(c0 + r) * outRS + r0 + sc] = *(const us4*)&Tl[r][sc];
    }
}

// ---------------------------------------------------------------------------
// split_T: fp32 [R][C] -> transposed bf16 hi/lo planes [C][R]  (prep_v)
// ---------------------------------------------------------------------------
__global__ __launch_bounds__(256) void split_T(const float* __restrict__ in, int inRS,
                                               u16* __restrict__ oh,
                                               u16* __restrict__ ol, int outRS) {
    __shared__ u16 Th[64][68], Tl[64][68];
    tsplit64(in, inRS, oh, ol, outRS,
             (size_t)blockIdx.y * 64, (size_t)blockIdx.x * 64, threadIdx.x, Th, Tl);
}

// ---------------------------------------------------------------------------
// prep_fused: one launch for the three input preps.
// blocks [0,1024):   x -> xh/xl (row-major split, grid-stride)
// blocks [1024,1792): w_qkv [1024][3072] -> wqkvT planes [3072][1024]
// blocks [1792,2048): w_proj [1024][1024] -> wprojT planes [1024][1024]
// ---------------------------------------------------------------------------
__global__ __launch_bounds__(256) void prep_fused(
    const float* __restrict__ x, const float* __restrict__ w_qkv,
    const float* __restrict__ w_proj,
    u16* __restrict__ xh, u16* __restrict__ xl,
    u16* __restrict__ wqh, u16* __restrict__ wql,
    u16* __restrict__ wph, u16* __restrict__ wpl) {
    __shared__ u16 Th[64][68], Tl[64][68];
    const int bid = blockIdx.x;
    const int tid = threadIdx.x;
    if (bid < 1024) {
        const int n4 = 4096 * 1024 / 4;
        int i = bid * 256 + tid;
        for (; i < n4; i += 1024 * 256) {
            f32x4 v = ((const f32x4*)x)[i];
            us4 h, l;
#pragma unroll
            for (int e = 0; e < 4; ++e) {
                u16 hb = f2bf(v[e]);
                h[e] = hb;
                l[e] = f2bf(v[e] - bf2f(hb));
            }
            ((us4*)xh)[i] = h;
            ((us4*)xl)[i] = l;
        }
    } else if (bid < 1792) {
        const int t = bid - 1024;              // 768 tiles = 48 x 16
        tsplit64(w_qkv, 3072, wqh, wql, 1024,
                 (size_t)(t / 48) * 64, (size_t)(t % 48) * 64, tid, Th, Tl);
    } else {
        const int t = bid - 1792;              // 256 tiles = 16 x 16
        tsplit64(w_proj, 1024, wph, wpl, 1024,
                 (size_t)(t / 16) * 64, (size_t)(t % 16) * 64, tid, Th, Tl);
    }
}

// ---------------------------------------------------------------------------
// gemm_bf2<BN>: C[M,N] = (Ah+Al)[M,K] @ (Bh+Bl)^T[N,K], split-bf16
// (hi*hi + hi*lo + lo*hi).  128xBN tile, BK=32, 256 thr (4 waves 2x2).
// global_load_lds staging, double-buffered, counted vmcnt, raw s_barrier.
// 2D XCD chunking: XCD x owns RBM x RBN block region (bm fastest inside).
// BN=192: LDS 2x40KB=80KB -> 2 blocks/CU exact. BN=64: 48KB -> 3/CU
// (launch_bounds min-waves 3: VGPR 88 < 170 budget, no new pressure).
// mode 1 (qkv, N=3072): per-n-frag section split -> scaled Q / K / fp32 V.
// ---------------------------------------------------------------------------
template <int BN>
__global__ __launch_bounds__(256, BN == 64 ? 3 : 2) void gemm_bf2(
    const u16* __restrict__ Ah_g, const u16* __restrict__ Al_g,
    const u16* __restrict__ Bh_g, const u16* __restrict__ Bl_g,
    int N, int K, int RM, int RBM, int RBN, int mode,
    float* __restrict__ Cf,
    u16* __restrict__ qsh, u16* __restrict__ qsl,
    u16* __restrict__ ksh, u16* __restrict__ ksl,
    float* __restrict__ vtmp) {
    constexpr int NB    = BN / 32;            // N-frags per wave
    constexpr int ASZ   = 128 * 32;           // u16 per A plane
    constexpr int BSZ   = BN * 32;
    constexpr int SET   = 2 * ASZ + 2 * BSZ;  // one buffer set (4 planes)
    constexpr int BCALL = BN / 64;            // B calls per plane per wave
    constexpr int NCALL = 4 + 2 * BCALL;      // per-wave calls per set
    __shared__ u16 LB[2 * SET];

    const int tid  = threadIdx.x;
    const int lane = tid & 63;
    const int w    = tid >> 6;

    // 2D XCD chunking: x = XCD id, j = index within its RBM x RBN region
    const int x = blockIdx.x & 7;
    const int j = blockIdx.x >> 3;
    const int bm = ((x % RM) * RBM + j % RBM) * 128;
    const int bn = ((x / RM) * RBN + j / RBM) * BN;

    // staging source geometry: call covers 16 rows; lane -> (row, phys chunk)
    const int srow = lane >> 2;                      // 0..15
    const int c_l  = (lane & 3) ^ ((lane >> 3) & 3); // inverse-swizzled chunk

    const u16* pA[2][2];
    const u16* pB[2][BCALL];
#pragma unroll
    for (int jj = 0; jj < 2; ++jj) {
        const size_t r = (size_t)(bm + w * 32 + jj * 16 + srow);
        pA[0][jj] = Ah_g + r * K + c_l * 8;
        pA[1][jj] = Al_g + r * K + c_l * 8;
    }
#pragma unroll
    for (int jj = 0; jj < BCALL; ++jj) {
        const size_t r = (size_t)(bn + w * (BN / 4) + jj * 16 + srow);
        pB[0][jj] = Bh_g + r * K + c_l * 8;
        pB[1][jj] = Bl_g + r * K + c_l * 8;
    }

    auto stage = [&](int buf, int kt) {
        u16* s = LB + buf * SET;
        const size_t ko = (size_t)kt * 32;
#pragma unroll
        for (int p = 0; p < 2; ++p)
#pragma unroll
            for (int jj = 0; jj < 2; ++jj)
                gl_lds16(pA[p][jj] + ko, s + p * ASZ + (w * 32 + jj * 16) * 32);
#pragma unroll
        for (int p = 0; p < 2; ++p)
#pragma unroll
            for (int jj = 0; jj < BCALL; ++jj)
                gl_lds16(pB[p][jj] + ko,
                         s + 2 * ASZ + p * BSZ + (w * (BN / 4) + jj * 16) * 32);
    };

    const int lr = lane & 15;
    const int lg = lane >> 4;
    const int wm = (w >> 1) * 64;
    const int wn = (w & 1) * (BN / 2);
    const int fc = (lg ^ ((lr >> 1) & 3)) * 8;  // phys chunk offset (u16)

    f32x4 acc[4][NB] = {};

    const int NK = K >> 5;
    stage(0, 0);
    if (NK > 1) stage(1, 1);

    for (int kt = 0; kt < NK; ++kt) {
        const int cur = kt & 1;
        if (kt + 1 < NK) wait_vmcnt<NCALL>();   // own set(kt) landed
        else             wait_vmcnt<0>();
        __builtin_amdgcn_s_barrier();           // all waves' set(kt) landed

        const u16* s = LB + cur * SET;
        bf16x8 fah[4], fal[4], fbh[NB], fbl[NB];
#pragma unroll
        for (int m = 0; m < 4; ++m) {
            const int ro = (wm + m * 16 + lr) * 32 + fc;
            fah[m] = __builtin_bit_cast(bf16x8, *(const us8*)(s + ro));
            fal[m] = __builtin_bit_cast(bf16x8, *(const us8*)(s + ASZ + ro));
        }
#pragma unroll
        for (int n = 0; n < NB; ++n) {
            const int ro = (wn + n * 16 + lr) * 32 + fc;
            fbh[n] = __builtin_bit_cast(bf16x8, *(const us8*)(s + 2 * ASZ + ro));
            fbl[n] = __builtin_bit_cast(bf16x8, *(const us8*)(s + 2 * ASZ + BSZ + ro));
        }
#pragma unroll
        for (int m = 0; m < 4; ++m)
#pragma unroll
            for (int n = 0; n < NB; ++n) {
                acc[m][n] = __builtin_amdgcn_mfma_f32_16x16x32_bf16(fah[m], fbh[n], acc[m][n], 0, 0, 0);
                acc[m][n] = __builtin_amdgcn_mfma_f32_16x16x32_bf16(fah[m], fbl[n], acc[m][n], 0, 0, 0);
                acc[m][n] = __builtin_amdgcn_mfma_f32_16x16x32_bf16(fal[m], fbh[n], acc[m][n], 0, 0, 0);
            }

        asm volatile("s_waitcnt lgkmcnt(0)" ::: "memory");  // own reads done
        __builtin_amdgcn_s_barrier();                       // all reads done
        if (kt + 2 < NK) stage(cur, kt + 2);                // refill freed buf
    }

    // epilogue: C/D layout col=lane&15, row=lg*4+reg
    const int orow = bm + wm + lg * 4;
    if (mode == 0) {
        const int ocol = bn + wn + lr;
#pragma unroll
        for (int m = 0; m < 4; ++m)
#pragma unroll
            for (int r = 0; r < 4; ++r) {
                const size_t row = (size_t)(orow + m * 16 + r);
#pragma unroll
                for (int n = 0; n < NB; ++n)
                    Cf[row * N + ocol + n * 16] = acc[m][n][r];
            }
    } else {
        // sections of 1024 cols: 0=Q(scale 1/8, split), 1=K(split), 2=V(f32)
#pragma unroll
        for (int n = 0; n < NB; ++n) {
            const int col  = bn + wn + n * 16 + lr;  // sec uniform per n-frag
            const int sec  = col >> 10;
            const int cidx = col & 1023;
#pragma unroll
            for (int m = 0; m < 4; ++m)
#pragma unroll
                for (int r = 0; r < 4; ++r) {
                    float v = acc[m][n][r];
                    const size_t idx = (size_t)(orow + m * 16 + r) * 1024 + cidx;
                    if (sec == 0) {
                        v *= 0.125f;
                        u16 hb = f2bf(v);
                        qsh[idx] = hb;
                        qsl[idx] = f2bf(v - bf2f(hb));
                    } else if (sec == 1) {
                        u16 hb = f2bf(v);
                        ksh[idx] = hb;
                        ksl[idx] = f2bf(v - bf2f(hb));
                    } else {
                        vtmp[idx] = v;
                    }
                }
        }
    }
}

// ---------------------------------------------------------------------------
// attn_v2: flash causal attention, pipelined global_load_lds staging.
// (unchanged: 118.5 µs, ~925 TF effective)
// ---------------------------------------------------------------------------
__global__ __launch_bounds__(512, 4) void attn_v2(
    const u16* __restrict__ qsh, const u16* __restrict__ qsl,
    const u16* __restrict__ ksh, const u16* __restrict__ ksl,
    const u16* __restrict__ vth, const u16* __restrict__ vtl,
    u16* __restrict__ oh, u16* __restrict__ ol) {
    __shared__ u16 KH[4096], KL[4096], VH[4096], VL[4096];  // [64][64] linear
    __shared__ u16 Ph[128][72], Pl[128][72];                 // padded

    const int tid  = threadIdx.x;
    const int lane = tid & 63;
    const int w    = tid >> 6;
    const int wq0  = w * 16;
    const int lr   = lane & 15;
    const int lg   = lane >> 4;

    const int bid  = blockIdx.x;
    const int half = bid >> 8;
    const int idx  = bid & 255;
    const int bh   = idx & 31;
    const int jj   = idx >> 5;
    const int qt   = half ? jj : (15 - jj);
    const int b    = bh >> 4;
    const int h    = bh & 15;
    const int NT   = 2 * qt + 2;
    const size_t tokb = (size_t)b * 2048;

    const size_t qtok = tokb + (size_t)qt * 128 + wq0 + lr;
    const u16* qph = qsh + qtok * 1024 + h * 64 + lg * 8;
    const u16* qpl = qsl + qtok * 1024 + h * 64 + lg * 8;
    bf16x8 aqh[2], aql[2];
    aqh[0] = __builtin_bit_cast(bf16x8, *(const us8*)qph);
    aqh[1] = __builtin_bit_cast(bf16x8, *(const us8*)(qph + 32));
    aql[0] = __builtin_bit_cast(bf16x8, *(const us8*)qpl);
    aql[1] = __builtin_bit_cast(bf16x8, *(const us8*)(qpl + 32));

    const int rl    = lane >> 3;
    const int rbase = w * 8;
    const int cl    = (lane & 7) ^ rl;
    const u16* kh0 = ksh + (tokb + rbase + rl) * 1024 + h * 64 + cl * 8;
    const u16* kl0 = ksl + (tokb + rbase + rl) * 1024 + h * 64 + cl * 8;
    const u16* vh0 = vth + (size_t)(h * 64 + rbase + rl) * 4096 + tokb + cl * 8;
    const u16* vl0 = vtl + (size_t)(h * 64 + rbase + rl) * 4096 + tokb + cl * 8;
    u16* ldsKH = KH + rbase * 64;
    u16* ldsKL = KL + rbase * 64;
    u16* ldsVH = VH + rbase * 64;
    u16* ldsVL = VL + rbase * 64;

    gl_lds16(kh0, ldsKH);
    gl_lds16(kl0, ldsKL);
    gl_lds16(vh0, ldsVH);
    gl_lds16(vl0, ldsVL);

    float m_i[4], l_i[4];
    f32x4 acc_o[4] = {};
#pragma unroll
    for (int r = 0; r < 4; ++r) { m_i[r] = -1e30f; l_i[r] = 0.f; }

    for (int kt = 0; kt < NT; ++kt) {
        const int koff = kt * 64 - qt * 128;
        const bool active = !(kt == NT - 1 && wq0 < 64);

        asm volatile("s_waitcnt vmcnt(2)" ::: "memory");
        __builtin_amdgcn_s_barrier();

        f32x4 accs[4] = {};
        if (active) {
#pragma unroll
            for (int ks = 0; ks < 2; ++ks) {
                bf16x8 a0 = aqh[ks], a1 = aql[ks];
#pragma unroll
                for (int n = 0; n < 4; ++n) {
                    const int row = n * 16 + lr;
                    const u16* pk = KH + row * 64 + (((ks * 4 + lg) ^ (row & 7)) << 3);
                    bf16x8 bkh = __builtin_bit_cast(bf16x8, *(const us8*)pk);
                    bf16x8 bkl = __builtin_bit_cast(bf16x8, *(const us8*)(pk + 4096));
                    accs[n] = __builtin_amdgcn_mfma_f32_16x16x32_bf16(a0, bkh, accs[n], 0, 0, 0);
                    accs[n] = __builtin_amdgcn_mfma_f32_16x16x32_bf16(a0, bkl, accs[n], 0, 0, 0);
                    accs[n] = __builtin_amdgcn_mfma_f32_16x16x32_bf16(a1, bkh, accs[n], 0, 0, 0);
                }
            }
            if (koff + 63 > wq0) {
#pragma unroll
                for (int n = 0; n < 4; ++n)
#pragma unroll
                    for (int rr = 0; rr < 4; ++rr)
                        if (koff + n * 16 + lr > wq0 + 4 * lg + rr)
                            accs[n][rr] = -1e30f;
            }
#pragma unroll
            for (int rr = 0; rr < 4; ++rr) {
                float pm = fmaxf(fmaxf(accs[0][rr], accs[1][rr]),
                                 fmaxf(accs[2][rr], accs[3][rr]));
#pragma unroll
                for (int off = 1; off < 16; off <<= 1)
                    pm = fmaxf(pm, __shfl_xor(pm, off));
                float mnew  = fmaxf(m_i[rr], pm);
                float alpha = __expf(m_i[rr] - mnew);
                float ps = 0.f;
                const int prow = wq0 + 4 * lg + rr;
#pragma unroll
                for (int n = 0; n < 4; ++n) {
                    float p = __expf(accs[n][rr] - mnew);
                    u16 phb = f2bf(p);
                    Ph[prow][n * 16 + lr] = phb;
                    Pl[prow][n * 16 + lr] = f2bf(p - bf2f(phb));
                    ps += p;
                }
#pragma unroll
                for (int off = 1; off < 16; off <<= 1)
                    ps += __shfl_xor(ps, off);
                l_i[rr] = l_i[rr] * alpha + ps;
                m_i[rr] = mnew;
#pragma unroll
                for (int n = 0; n < 4; ++n) acc_o[n][rr] *= alpha;
            }
        }

        asm volatile("s_waitcnt vmcnt(0)" ::: "memory");
        asm volatile("s_waitcnt lgkmcnt(0)" ::: "memory");
        __builtin_amdgcn_s_barrier();

        if (kt + 1 < NT) {
            gl_lds16(kh0 + (size_t)(kt + 1) * 65536, ldsKH);
            gl_lds16(kl0 + (size_t)(kt + 1) * 65536, ldsKL);
        }

        if (active) {
#pragma unroll
            for (int ks = 0; ks < 2; ++ks) {
                bf16x8 aph = __builtin_bit_cast(bf16x8, *(const us8*)&Ph[wq0 + lr][ks * 32 + lg * 8]);
                bf16x8 apl = __builtin_bit_cast(bf16x8, *(const us8*)&Pl[wq0 + lr][ks * 32 + lg * 8]);
#pragma unroll
                for (int n = 0; n < 4; ++n) {
                    const int row = n * 16 + lr;
                    const u16* pv = VH + row * 64 + (((ks * 4 + lg) ^ (row & 7)) << 3);
                    bf16x8 bvh = __builtin_bit_cast(bf16x8, *(const us8*)pv);
                    bf16x8 bvl = __builtin_bit_cast(bf16x8, *(const us8*)(pv + 4096));
                    acc_o[n] = __builtin_amdgcn_mfma_f32_16x16x32_bf16(aph, bvh, acc_o[n], 0, 0, 0);
                    acc_o[n] = __builtin_amdgcn_mfma_f32_16x16x32_bf16(aph, bvl, acc_o[n], 0, 0, 0);
                    acc_o[n] = __builtin_amdgcn_mfma_f32_16x16x32_bf16(apl, bvh, acc_o[n], 0, 0, 0);
                }
            }
        }

        asm volatile("s_waitcnt lgkmcnt(0)" ::: "memory");
        __builtin_amdgcn_s_barrier();

        if (kt + 1 < NT) {
            gl_lds16(vh0 + (kt + 1) * 64, ldsVH);
            gl_lds16(vl0 + (kt + 1) * 64, ldsVL);
        }
    }

#pragma unroll
    for (int rr = 0; rr < 4; ++rr) {
        float inv = 1.0f / l_i[rr];
        const size_t q = (size_t)qt * 128 + wq0 + 4 * lg + rr;
#pragma unroll
        for (int n = 0; n < 4; ++n) {
            float v = acc_o[n][rr] * inv;
            const size_t oidx = (tokb + q) * 1024 + h * 64 + n * 16 + lr;
            u16 hb = f2bf(v);
            oh[oidx] = hb;
            ol[oidx] = f2bf(v - bf2f(hb));
        }
    }
}

// ---------------------------------------------------------------------------
// Workspace (80 MB), stream-ordered aliases:
//   0 wqkvT_h 6MB | 6 wqkvT_l | 12 wprojT_h 2MB | 14 wprojT_l
//   16 xh 8MB / 24 xl 8MB   (dead after gemm1 -> reused as vth/vtl)
//   32 qsh / 40 qsl / 48 ksh / 56 ksl (8MB each)
//   64 vtmp 16MB            (dead after prep_v -> reused as oh/ol)
// ---------------------------------------------------------------------------
extern "C" void kernel_launch(void* const* d_in, const int* in_sizes, int n_in,
                              void* d_out, int out_size, void* d_ws, size_t ws_size,
                              hipStream_t stream) {
    const float* x      = (const float*)d_in[0];
    const float* w_qkv  = (const float*)d_in[1];
    const float* w_proj = (const float*)d_in[2];
    float* out = (float*)d_out;

    char* ws = (char*)d_ws;
    const size_t MB = 1u << 20;
    u16* wqkvT_h  = (u16*)(ws + 0 * MB);
    u16* wqkvT_l  = (u16*)(ws + 6 * MB);
    u16* wprojT_h = (u16*)(ws + 12 * MB);
    u16* wprojT_l = (u16*)(ws + 14 * MB);
    u16* xh       = (u16*)(ws + 16 * MB);
    u16* xl       = (u16*)(ws + 24 * MB);
    u16* qsh      = (u16*)(ws + 32 * MB);
    u16* qsl      = (u16*)(ws + 40 * MB);
    u16* ksh      = (u16*)(ws + 48 * MB);
    u16* ksl      = (u16*)(ws + 56 * MB);
    float* vtmp   = (float*)(ws + 64 * MB);
    u16* vth = xh;
    u16* vtl = xl;
    u16* oh = (u16*)vtmp;
    u16* ol = oh + (size_t)4096 * 1024;

    // fused input preps: split x, transpose+split both weights
    prep_fused<<<dim3(2048), 256, 0, stream>>>(x, w_qkv, w_proj,
                                               xh, xl, wqkvT_h, wqkvT_l,
                                               wprojT_h, wprojT_l);

    // 1) qkv GEMM (M=4096,N=3072,K=1024): 128x192 tile, grid 32x16=512
    //    regions: RM=4 -> XCD owns 8x8 blocks (1536x1024 out chunk)
    gemm_bf2<192><<<dim3(512), 256, 0, stream>>>(xh, xl, wqkvT_h, wqkvT_l,
                                                 3072, 1024, 4, 8, 8, 1,
                                                 nullptr, qsh, qsl, ksh, ksl, vtmp);

    // prep_v: vtmp [4096][1024] -> transposed split planes [1024][4096]
    split_T<<<dim3(16, 64), 256, 0, stream>>>(vtmp, 1024, vth, vtl, 4096);

    // 2) pipelined flash causal attention
    attn_v2<<<dim3(512), 512, 0, stream>>>(qsh, qsl, ksh, ksl, vth, vtl, oh, ol);

    // 3) out = O @ w_proj (M=4096,N=1024,K=1024): BN=64, grid 32x16=512
    gemm_bf2<64><<<dim3(512), 256, 0, stream>>>(oh, ol, wprojT_h, wprojT_l,
                                                1024, 1024, 4, 8, 8, 0,
                                                out, nullptr, nullptr, nullptr, nullptr, nullptr);
}